// Round 7
// baseline (33.652 us; speedup 1.0000x reference)
//
#include <hip/hip_runtime.h>

#define NB 2
#define NCK 8                    // tracked components 1..8 (comp 0 dropped)
#define NVAL (NCK * 2)           // {inter,count} x 8 per batch
#define NSL 32                   // per-block partial row: b0[16] | b1[16]
#define SMOOTHF 1e-5f

// Per-thread private LDS bins: 9 float2 {inter,count}, row stride 18 floats,
// row base swizzled by +2 floats for odd (tid>>4) so lanes 16 apart land on
// different banks: 16*18=288==0 mod 32 (4-way conflict) -> 290==2 (none).
// Only dl=32 aliases (2-way, free). Base stays 8B-aligned for b64 ops.
#define TROW 18
#define RBASE(t) ((t) * TROW + ((((t) >> 4) & 1) << 1))

__global__ __launch_bounds__(256) void cc_accum(
        const float* __restrict__ y_pred,
        const int* __restrict__ y,
        const int* __restrict__ comp,
        float* __restrict__ partial,   // [nblk][NSL] row-major
        int V4, int BPB) {
    __shared__ __align__(8) float sacc[256 * TROW + 4 + 16 * 16];
    float* redbuf = &sacc[256 * TROW + 4];

    float2* mybins = (float2*)&sacc[RBASE(threadIdx.x)];
    #pragma unroll
    for (int i = 0; i < 9; ++i) mybins[i] = make_float2(0.0f, 0.0f);
    // no barrier needed: each thread touches only its own row until drain

    const int b   = (blockIdx.x >= BPB) ? 1 : 0;   // batch is block-uniform
    const int blk = blockIdx.x - b * BPB;
    const int stride = BPB * 256;

    const float* p0 = y_pred + (size_t)b * 2 * ((size_t)V4 * 4);
    const float* p1 = p0 + (size_t)V4 * 4;
    const int4* yq = (const int4*)y    + (size_t)b * V4;
    const int4* cq = (const int4*)comp + (size_t)b * V4;

    for (int v = blk * 256 + threadIdx.x; v < V4; v += stride) {
        const float4 a0 = ((const float4*)p0)[v];
        const float4 a1 = ((const float4*)p1)[v];
        const int4 t = yq[v];
        const int4 c = cq[v];

        // p_true = softmax(y_pred)[true] = 1/(1+exp(t ? a0-a1 : a1-a0))
        {
            const float d = a0.x - a1.x;
            const float p = 1.0f / (1.0f + __expf(t.x ? d : -d));
            float2 s = mybins[c.x]; s.x += p; s.y += 1.0f; mybins[c.x] = s;
        }
        {
            const float d = a0.y - a1.y;
            const float p = 1.0f / (1.0f + __expf(t.y ? d : -d));
            float2 s = mybins[c.y]; s.x += p; s.y += 1.0f; mybins[c.y] = s;
        }
        {
            const float d = a0.z - a1.z;
            const float p = 1.0f / (1.0f + __expf(t.z ? d : -d));
            float2 s = mybins[c.z]; s.x += p; s.y += 1.0f; mybins[c.z] = s;
        }
        {
            const float d = a0.w - a1.w;
            const float p = 1.0f / (1.0f + __expf(t.w ? d : -d));
            float2 s = mybins[c.w]; s.x += p; s.y += 1.0f; mybins[c.w] = s;
        }
    }
    __syncthreads();

    // Drain: value v = tid&15 (v = 2*(comp-1)+part), group g = tid>>4 sums 16 rows.
    {
        const int vv = threadIdx.x & 15, g = threadIdx.x >> 4;
        const int off = ((vv >> 1) + 1) * 2 + (vv & 1);   // skip bin 0
        float s = 0.0f;
        #pragma unroll
        for (int k = 0; k < 16; ++k)
            s += sacc[RBASE(g * 16 + k) + off];
        redbuf[vv * 16 + g] = s;
    }
    __syncthreads();
    // One 128B row per block: [32] = b0 vals | b1 vals (other batch zeroed).
    if (threadIdx.x < NSL) {
        const int j = threadIdx.x, jb = j >> 4, jv = j & 15;
        float s = 0.0f;
        if (jb == b) {
            #pragma unroll
            for (int g = 0; g < 16; ++g) s += redbuf[jv * 16 + g];
        }
        partial[(size_t)blockIdx.x * NSL + j] = s;
    }
}

// Fused reduce+final: one block, 1024 threads, column-sum of [nblk][32].
// float4 f covers vals 4*(f%8)..+3; f%8 == tid%8 is per-thread constant.
__global__ __launch_bounds__(1024) void cc_finish(
        const float* __restrict__ partial, float* __restrict__ out, int nblk) {
    const int tid = threadIdx.x;
    const float4* p4 = (const float4*)partial;
    const int nf = nblk * (NSL / 4);

    float4 a = make_float4(0.f, 0.f, 0.f, 0.f);
    for (int f = tid; f < nf; f += 1024) {
        const float4 v = p4[f];
        a.x += v.x; a.y += v.y; a.z += v.z; a.w += v.w;
    }

    __shared__ float4 red[1024];
    red[tid] = a;
    __syncthreads();
    if (tid < 256) {
        float4 r = red[tid];
        const float4 s1 = red[tid + 256], s2 = red[tid + 512], s3 = red[tid + 768];
        r.x += s1.x + s2.x + s3.x;
        r.y += s1.y + s2.y + s3.y;
        r.z += s1.z + s2.z + s3.z;
        r.w += s1.w + s2.w + s3.w;
        red[tid] = r;
    }
    __syncthreads();
    if (tid < 64) {
        float4 r = red[tid];
        const float4 s1 = red[tid + 64], s2 = red[tid + 128], s3 = red[tid + 192];
        r.x += s1.x + s2.x + s3.x;
        r.y += s1.y + s2.y + s3.y;
        r.z += s1.z + s2.z + s3.z;
        r.w += s1.w + s2.w + s3.w;
        red[tid] = r;
    }
    __syncthreads();
    __shared__ float fin[NSL];
    if (tid < NSL) {
        const int grp = tid >> 2, k = tid & 3;   // contributors: row = g*8 + grp
        float s = 0.0f;
        #pragma unroll
        for (int g = 0; g < 8; ++g) {
            const float4 r = red[g * 8 + grp];
            s += (k == 0) ? r.x : (k == 1) ? r.y : (k == 2) ? r.z : r.w;
        }
        fin[tid] = s;
    }
    __syncthreads();
    if (tid == 0) {
        // psum = tsum = count (softmax over 2 ch sums to 1; one-hot sums to 1)
        float total = 0.0f;
        for (int b = 0; b < NB; ++b) {
            float dsum = 0.0f, pc = 0.0f;
            for (int j = 0; j < NCK; ++j) {
                const float inter = fin[b * NVAL + 2 * j];
                const float cnt   = fin[b * NVAL + 2 * j + 1];
                if (cnt > 0.0f) {
                    dsum += 1.0f - (2.0f * inter + SMOOTHF) / (2.0f * cnt + SMOOTHF);
                    pc += 1.0f;
                }
            }
            total += dsum / fmaxf(pc, 1.0f);
        }
        out[0] = total / (float)NB;
    }
}

extern "C" void kernel_launch(void* const* d_in, const int* in_sizes, int n_in,
                              void* d_out, int out_size, void* d_ws, size_t ws_size,
                              hipStream_t stream) {
    const float* y_pred = (const float*)d_in[0];
    const int*   y      = (const int*)d_in[1];
    const int*   comp   = (const int*)d_in[2];
    float* out = (float*)d_out;
    float* ws  = (float*)d_ws;

    const int nvox = in_sizes[1];    // B * V = 8,192,000
    const int V    = nvox / NB;      // 4,096,000
    const int V4   = V / 4;          // 1,024,000 quads per batch

    int BPB = 1024;                  // blocks per batch -> 2048 total = 8/CU
    int cap_rows = (int)(ws_size / (NSL * sizeof(float)));
    if (2 * BPB > cap_rows) BPB = cap_rows / 2;
    if (BPB > V4) BPB = V4;
    if (BPB < 1) BPB = 1;
    const int nblk = 2 * BPB;

    cc_accum<<<dim3(nblk), dim3(256), 0, stream>>>(y_pred, y, comp, ws, V4, BPB);
    cc_finish<<<dim3(1), dim3(1024), 0, stream>>>(ws, out, nblk);
}